// Round 3
// baseline (336.519 us; speedup 1.0000x reference)
//
#include <hip/hip_runtime.h>
#include <hip/hip_bf16.h>
#include <math.h>

#define Bsz 2
#define Sq  2048
#define Dm  2048
#define Hn  16
#define KVn 4
#define HDn 128

typedef __attribute__((ext_vector_type(8))) short bf16x8;
typedef __attribute__((ext_vector_type(4))) float f32x4;

__device__ __forceinline__ short f2b(float f) {
    __hip_bfloat16 h = __float2bfloat16(f);
    return *reinterpret_cast<short*>(&h);
}
__device__ __forceinline__ float b2f(short s) {
    __hip_bfloat16 h = *reinterpret_cast<__hip_bfloat16*>(&s);
    return __bfloat162float(h);
}

// ---------------- fp32 -> bf16 elementwise (x) ----------------
__global__ __launch_bounds__(256) void f2b_kernel(
    const float* __restrict__ X, short* __restrict__ Y, int n4)
{
    int i = blockIdx.x * 256 + threadIdx.x;
    if (i >= n4) return;
    float4 v = ((const float4*)X)[i];
    short4 o;
    o.x = f2b(v.x); o.y = f2b(v.y); o.z = f2b(v.z); o.w = f2b(v.w);
    ((short4*)Y)[i] = o;
}

// ------------- ALL weights -> transposed bf16 in one launch -------------
__global__ __launch_bounds__(256) void wconv_all_kernel(
    const float* __restrict__ wq, const float* __restrict__ wk,
    const float* __restrict__ wv, const float* __restrict__ wo,
    short* __restrict__ wqkvT, short* __restrict__ woT)
{
    __shared__ float t[32][33];
    const int n0 = blockIdx.x * 32;   // global output row
    const int k0 = blockIdx.y * 32;
    const int tx = threadIdx.x, ty = threadIdx.y;

    const float* W; int Nsec, nloc; short* dst;
    if (n0 < 2048)      { W = wq; Nsec = 2048; nloc = n0;        dst = wqkvT + (size_t)n0 * Dm; }
    else if (n0 < 2560) { W = wk; Nsec = 512;  nloc = n0 - 2048; dst = wqkvT + (size_t)n0 * Dm; }
    else if (n0 < 3072) { W = wv; Nsec = 512;  nloc = n0 - 2560; dst = wqkvT + (size_t)n0 * Dm; }
    else                { W = wo; Nsec = 2048; nloc = n0 - 3072; dst = woT + (size_t)(n0 - 3072) * Dm; }

#pragma unroll
    for (int r = 0; r < 4; ++r) {
        const int row = ty + 8 * r;
        t[row][tx] = W[(size_t)(k0 + row) * Nsec + nloc + tx];
    }
    __syncthreads();
#pragma unroll
    for (int r = 0; r < 4; ++r) {
        const int row = ty + 8 * r;
        dst[(size_t)row * Dm + k0 + tx] = f2b(t[tx][row]);
    }
}

// ---------------- bf16 MFMA GEMM: C(MxN) = A(MxK) * Bt(NxK)^T ----------------
template <typename OT>
__global__ __launch_bounds__(256) void gemm_bt_kernel(
    const short* __restrict__ A, const short* __restrict__ Bt,
    OT* __restrict__ C, int M, int N, int K)
{
    __shared__ __align__(16) short As[128 * 64];
    __shared__ __align__(16) short Bs[128 * 64];

    const int tid  = threadIdx.x;
    const int w    = tid >> 6;
    const int lane = tid & 63;
    const int m16  = lane & 15;
    const int g4   = lane >> 4;
    const int wm   = w >> 1, wn = w & 1;

    const int row0 = blockIdx.y * 128;
    const int col0 = blockIdx.x * 128;

    const short* Ab = A  + (size_t)row0 * K;
    const short* Bb = Bt + (size_t)col0 * K;

    const int trow = tid >> 3;
    const int soct = (tid & 7) ^ (trow & 7);

    f32x4 acc[4][4];
#pragma unroll
    for (int i = 0; i < 4; ++i)
#pragma unroll
        for (int j = 0; j < 4; ++j) acc[i][j] = (f32x4){0.f, 0.f, 0.f, 0.f};

    for (int k0 = 0; k0 < K; k0 += 64) {
#pragma unroll
        for (int r = 0; r < 4; ++r) {
            const short* gp = Ab + (size_t)(r * 32 + trow) * K + k0 + soct * 8;
            short* lp = &As[(size_t)(r * 256 + w * 64) * 8];
            __builtin_amdgcn_global_load_lds(
                (const __attribute__((address_space(1))) void*)gp,
                (__attribute__((address_space(3))) void*)lp, 16, 0, 0);
        }
#pragma unroll
        for (int r = 0; r < 4; ++r) {
            const short* gp = Bb + (size_t)(r * 32 + trow) * K + k0 + soct * 8;
            short* lp = &Bs[(size_t)(r * 256 + w * 64) * 8];
            __builtin_amdgcn_global_load_lds(
                (const __attribute__((address_space(1))) void*)gp,
                (__attribute__((address_space(3))) void*)lp, 16, 0, 0);
        }
        __syncthreads();

#pragma unroll
        for (int kc = 0; kc < 2; ++kc) {
            bf16x8 a[4], b[4];
            const int swz = (kc * 4 + g4) ^ (m16 & 7);
#pragma unroll
            for (int s = 0; s < 4; ++s) {
                const int rowA = wm * 64 + s * 16 + m16;
                a[s] = *(const bf16x8*)&As[rowA * 64 + swz * 8];
                const int rowB = wn * 64 + s * 16 + m16;
                b[s] = *(const bf16x8*)&Bs[rowB * 64 + swz * 8];
            }
#pragma unroll
            for (int i = 0; i < 4; ++i)
#pragma unroll
                for (int j = 0; j < 4; ++j)
                    acc[i][j] = __builtin_amdgcn_mfma_f32_16x16x32_bf16(
                        a[i], b[j], acc[i][j], 0, 0, 0);
        }
        __syncthreads();
    }

#pragma unroll
    for (int i = 0; i < 4; ++i) {
        const int mbase = row0 + wm * 64 + i * 16 + g4 * 4;
#pragma unroll
        for (int j = 0; j < 4; ++j) {
            const int n = col0 + wn * 64 + j * 16 + m16;
#pragma unroll
            for (int r = 0; r < 4; ++r) {
                if constexpr (sizeof(OT) == 2)
                    C[(size_t)(mbase + r) * N + n] = f2b(acc[i][j][r]);
                else
                    C[(size_t)(mbase + r) * N + n] = acc[i][j][r];
            }
        }
    }
}

// ------------- RoPE (Q and K in one launch): one thread per (b,s,i) -------------
__global__ __launch_bounds__(256) void rope_all_kernel(
    const short* __restrict__ C3b, short* __restrict__ Qb, short* __restrict__ Kb,
    const int* __restrict__ pos_ids, float qscale, int total)
{
    int idx = blockIdx.x * blockDim.x + threadIdx.x;
    if (idx >= total) return;
    const int i = idx & 63;
    int rest = idx >> 6;
    const int s = rest % Sq;
    const int b = rest / Sq;

    const int pos = pos_ids[b * Sq + s];
    const float e   = -(float)(2 * i) * (1.0f / (float)HDn);
    const float inv = exp2f(e * 18.931568569324174f);   // log2(500000)
    const float f   = (float)pos * inv;
    float sn, c;
    sincosf(f, &sn, &c);

    const short* src = C3b + ((size_t)(b * Sq + s)) * 3072;

#pragma unroll
    for (int h = 0; h < Hn; ++h) {
        const float x1 = b2f(src[h * HDn + i]);
        const float x2 = b2f(src[h * HDn + i + 64]);
        const size_t dst = (((size_t)b * Hn + h) * Sq + s) * HDn;
        Qb[dst + i]      = f2b((x1 * c - x2 * sn) * qscale);
        Qb[dst + i + 64] = f2b((x2 * c + x1 * sn) * qscale);
    }
#pragma unroll
    for (int h = 0; h < KVn; ++h) {
        const float x1 = b2f(src[2048 + h * HDn + i]);
        const float x2 = b2f(src[2048 + h * HDn + i + 64]);
        const size_t dst = (((size_t)b * KVn + h) * Sq + s) * HDn;
        Kb[dst + i]      = f2b(x1 * c - x2 * sn);
        Kb[dst + i + 64] = f2b(x2 * c + x1 * sn);
    }
}

// ------------- V region of bf16 C3 -> transposed (B,KV,HD,S) bf16 -------------
__global__ __launch_bounds__(256) void vconv_kernel(
    const short* __restrict__ C3b, short* __restrict__ Vt)
{
    __shared__ short t[32][34];
    const int bk = blockIdx.z;
    const int b  = bk >> 2, kv = bk & 3;
    const int s0 = blockIdx.x * 32;
    const int d0 = blockIdx.y * 32;
    const int tx = threadIdx.x, ty = threadIdx.y;

#pragma unroll
    for (int r = 0; r < 4; ++r) {
        const int row = ty + 8 * r;
        t[row][tx] = C3b[((size_t)(b * Sq + s0 + row)) * 3072 + 2560 + kv * HDn + d0 + tx];
    }
    __syncthreads();
#pragma unroll
    for (int r = 0; r < 4; ++r) {
        const int row = ty + 8 * r;
        Vt[((size_t)bk * HDn + d0 + row) * Sq + s0 + tx] = t[tx][row];
    }
}

// ------------- Block-cooperative MFMA flash attention, KQ orientation -------------
// UNIFORM + AMORTIZED version: 8 waves (512 threads), 128-q jobs. Block p runs
// the complementary 128-row tile pair (qtA=15-p, qtB=p) sequentially:
// (2*qtA+2) + (2*qtB+2) = 34 chunks for EVERY block -> uniform. 256 blocks =
// 1/CU (2 waves/SIMD), but staging bytes / barriers / stage-issue per CU are
// HALVED vs the 64-q version (8 waves share each 32KB K/V chunk). Masking
// spans the last two chunks of each job (128-row tile diagonal = 2 chunks);
// fully-masked waves skip compute on the final chunk.
__global__ __launch_bounds__(512, 2) void fattn_kernel(
    const short* __restrict__ Qb, const short* __restrict__ Kb,
    const short* __restrict__ Vtb, short* __restrict__ AOb)
{
    __shared__ __align__(16) short Ks[2][64 * 128];   // [buf][perm key][dim], oct-swizzled
    __shared__ __align__(16) short Vs[2][128 * 64];   // [buf][dim][key], oct-swizzled

    const int tid  = threadIdx.x;
    const int w    = tid >> 6;        // 0..7
    const int lane = tid & 63;
    const int m16  = lane & 15;
    const int g4   = lane >> 4;

    // block -> (b, h, pair p)
    const int p  = blockIdx.x & 7;
    const int h  = (blockIdx.x >> 3) & 15;
    const int b  = blockIdx.x >> 7;
    const int kv = h >> 2;

    const int qtA = 15 - p, qtB = p;
    const int nchA = 2 * qtA + 2, nchB = 2 * qtB + 2;   // sums to 34 always
    const int qbA = qtA << 7, qbB = qtB << 7;

    // Q fragments for both jobs (static indexing via separate arrays)
    bf16x8 qfA[4], qfB[4];
    {
        const short* qpA = Qb + (((size_t)b * Hn + h) * Sq + qbA + w * 16 + m16) * HDn + g4 * 8;
        const short* qpB = Qb + (((size_t)b * Hn + h) * Sq + qbB + w * 16 + m16) * HDn + g4 * 8;
#pragma unroll
        for (int c = 0; c < 4; ++c) {
            qfA[c] = *(const bf16x8*)(qpA + c * 32);
            qfB[c] = *(const bf16x8*)(qpB + c * 32);
        }
    }

    const short* kbase = Kb  + ((size_t)b * KVn + kv) * Sq * HDn;
    const short* vbase = Vtb + ((size_t)b * KVn + kv) * (size_t)HDn * Sq;

    // staging source pointers (loop-invariant part); 512 threads x r=0..1 x 16B
    const short* gpK[2];
    const short* gpV[2];
#pragma unroll
    for (int r = 0; r < 2; ++r) {
        const int ci = r * 512 + tid;
        const int R  = ci >> 4, o = ci & 15;          // LDS K row, oct
        const int hf = (R >> 5) & 1, Rl = R & 31;
        const int phys = hf * 32 + ((Rl >> 2) & 3) * 8 + ((Rl >> 4) & 1) * 4 + (Rl & 3);
        gpK[r] = kbase + (size_t)phys * HDn + (o ^ (R & 7)) * 8;
        const int d = ci >> 3, ov = ci & 7;           // V dim row, oct
        gpV[r] = vbase + (size_t)d * Sq + (ov ^ (d & 7)) * 8;
    }

    auto stage = [&](int ktE, int buf) {
#pragma unroll
        for (int r = 0; r < 2; ++r) {
            const short* gp = gpK[r] + (size_t)ktE * HDn;
            short* lp = &Ks[buf][(size_t)(r * 512 + w * 64) * 8];
            __builtin_amdgcn_global_load_lds(
                (const __attribute__((address_space(1))) void*)gp,
                (__attribute__((address_space(3))) void*)lp, 16, 0, 0);
        }
#pragma unroll
        for (int r = 0; r < 2; ++r) {
            const short* gp = gpV[r] + ktE;
            short* lp = &Vs[buf][(size_t)(r * 512 + w * 64) * 8];
            __builtin_amdgcn_global_load_lds(
                (const __attribute__((address_space(1))) void*)gp,
                (__attribute__((address_space(3))) void*)lp, 16, 0, 0);
        }
    };

    f32x4 Ot[8];
#pragma unroll
    for (int t = 0; t < 8; ++t) Ot[t] = (f32x4){0.f, 0.f, 0.f, 0.f};
    float mcur = -1e30f, lcur = 0.f;
    int gpar = 0;

    auto run_job = [&](const bf16x8 (&qf)[4], int nch, int qb, bool lastJob) {
        for (int ch = 0; ch < nch; ++ch) {
            const int cur = gpar & 1;
            gpar ^= 1;
            const int kt = ch << 6;

            __syncthreads();   // staging of buf[cur] complete; buf[cur^1] readers done
            if (ch + 1 < nch)      stage((ch + 1) << 6, cur ^ 1);
            else if (!lastJob)     stage(0, cur ^ 1);   // prefetch next job's chunk 0

            const bool last = (ch == nch - 1);
            // waves 0..3 are entirely above the last key chunk -> fully masked; skip.
            if (last && w < 4) continue;

            const bool dg = (ch >= nch - 2);   // 128-row tile diagonal spans 2 chunks
            const short* KsC = Ks[cur];
            const short* VsC = Vs[cur];

            // ---- scores: one 16q x 64k tile per wave ----
            f32x4 sc[4];
            __builtin_amdgcn_s_setprio(1);
#pragma unroll
            for (int f = 0; f < 4; ++f) {
                f32x4 a = (f32x4){0.f, 0.f, 0.f, 0.f};
                const int krow = f * 16 + m16;
#pragma unroll
                for (int c = 0; c < 4; ++c) {
                    bf16x8 kf = *(const bf16x8*)&KsC[krow * 128 + (((c * 4 + g4) ^ (m16 & 7)) * 8)];
                    a = __builtin_amdgcn_mfma_f32_16x16x32_bf16(kf, qf[c], a, 0, 0, 0);
                }
                sc[f] = a;
            }
            __builtin_amdgcn_s_setprio(0);

            // ---- causal mask (two diagonal chunks) ----
            if (dg) {
                const int qg = qb + w * 16 + m16;
#pragma unroll
                for (int f = 0; f < 4; ++f)
#pragma unroll
                    for (int ii = 0; ii < 4; ++ii) {
                        const int kg = kt + (f >> 1) * 32 + g4 * 8 + (f & 1) * 4 + ii;
                        if (kg > qg) sc[f][ii] = -1e30f;
                    }
            }

            // ---- online softmax (T13 defer-max, THR=8 in exp2 domain) ----
            float mx = sc[0][0];
#pragma unroll
            for (int f = 0; f < 4; ++f)
#pragma unroll
                for (int ii = 0; ii < 4; ++ii) mx = fmaxf(mx, sc[f][ii]);
            mx = fmaxf(mx, __shfl_xor(mx, 16));
            mx = fmaxf(mx, __shfl_xor(mx, 32));
            if (!__all(mx <= mcur + 8.0f)) {
                const float nm = fmaxf(mcur, mx);
                const float alpha = exp2f(mcur - nm);
                mcur = nm;
                lcur *= alpha;
#pragma unroll
                for (int t = 0; t < 8; ++t)
#pragma unroll
                    for (int ii = 0; ii < 4; ++ii) Ot[t][ii] *= alpha;
            }
            float ps = 0.f;
#pragma unroll
            for (int f = 0; f < 4; ++f)
#pragma unroll
                for (int ii = 0; ii < 4; ++ii) {
                    sc[f][ii] = exp2f(sc[f][ii] - mcur);
                    ps += sc[f][ii];
                }
            ps += __shfl_xor(ps, 16);
            ps += __shfl_xor(ps, 32);
            lcur += ps;

            bf16x8 pf[2];
#pragma unroll
            for (int hf = 0; hf < 2; ++hf) {
                bf16x8 pk;
#pragma unroll
                for (int j8 = 0; j8 < 8; ++j8)
                    pk[j8] = f2b(j8 < 4 ? sc[hf * 2][j8] : sc[hf * 2 + 1][j8 - 4]);
                pf[hf] = pk;
            }

            // ---- PV: O^T[d][q] += V^T[d][k] * P[k][q] ----
            __builtin_amdgcn_s_setprio(1);
#pragma unroll
            for (int t = 0; t < 8; ++t) {
                const int d = t * 16 + m16;
                bf16x8 vfa = *(const bf16x8*)&VsC[d * 64 + ((g4 ^ (d & 7)) * 8)];
                bf16x8 vfb = *(const bf16x8*)&VsC[d * 64 + (((4 + g4) ^ (d & 7)) * 8)];
                Ot[t] = __builtin_amdgcn_mfma_f32_16x16x32_bf16(vfa, pf[0], Ot[t], 0, 0, 0);
                Ot[t] = __builtin_amdgcn_mfma_f32_16x16x32_bf16(vfb, pf[1], Ot[t], 0, 0, 0);
            }
            __builtin_amdgcn_s_setprio(0);
        }
    };

    auto writeO = [&](int qb) {
        const float inv = 1.0f / lcur;
        short* op = AOb + ((size_t)(b * Sq + qb + w * 16 + m16)) * (Hn * HDn) + h * HDn + g4 * 4;
#pragma unroll
        for (int t = 0; t < 8; ++t) {
            short4 o;
            o.x = f2b(Ot[t][0] * inv);
            o.y = f2b(Ot[t][1] * inv);
            o.z = f2b(Ot[t][2] * inv);
            o.w = f2b(Ot[t][3] * inv);
            *(short4*)(op + t * 16) = o;
        }
    };

    stage(0, 0);
    run_job(qfA, nchA, qbA, false);
    writeO(qbA);
#pragma unroll
    for (int t = 0; t < 8; ++t) Ot[t] = (f32x4){0.f, 0.f, 0.f, 0.f};
    mcur = -1e30f; lcur = 0.f;
    run_job(qfB, nchB, qbB, true);
    writeO(qbB);
}

extern "C" void kernel_launch(void* const* d_in, const int* in_sizes, int n_in,
                              void* d_out, int out_size, void* d_ws, size_t ws_size,
                              hipStream_t stream)
{
    const float* x   = (const float*)d_in[0];
    const float* wq  = (const float*)d_in[1];
    const float* wk  = (const float*)d_in[2];
    const float* wv  = (const float*)d_in[3];
    const float* wo  = (const float*)d_in[4];
    const int* pos   = (const int*)d_in[6];
    float* out = (float*)d_out;

    const int M = Bsz * Sq;            // 4096
    const size_t nX  = (size_t)M * Dm; // 8388608

    short* xb    = (short*)d_ws;
    short* wqkvT = xb + nX;                       // 3072 x 2048
    short* woT   = wqkvT + (size_t)3072 * Dm;     // 2048 x 2048
    short* C3b   = woT + (size_t)Dm * Dm;         // 4096 x 3072 bf16
    short* Qb    = C3b + (size_t)M * 3072;
    short* Kb    = Qb + nX;
    short* Vtb   = Kb + (size_t)Bsz * KVn * Sq * HDn;
    short* AOb   = Vtb + (size_t)Bsz * KVn * Sq * HDn;

    // --- conversions (2 launches) ---
    f2b_kernel<<<(nX / 4 + 255) / 256, 256, 0, stream>>>(x, xb, nX / 4);
    wconv_all_kernel<<<dim3(5120 / 32, Dm / 32), dim3(32, 8), 0, stream>>>(
        wq, wk, wv, wo, wqkvT, woT);

    // --- fused QKV projection -> bf16 C3 ---
    gemm_bt_kernel<short><<<dim3(3072 / 128, M / 128), 256, 0, stream>>>(
        xb, wqkvT, C3b, M, 3072, Dm);

    // --- RoPE (Q+K) in one launch ---
    {
        const float qscale = 0.08838834764831845f * 1.4426950408889634f;
        int tot = Bsz * Sq * 64;
        rope_all_kernel<<<(tot + 255) / 256, 256, 0, stream>>>(
            C3b, Qb, Kb, pos, qscale, tot);
    }
    vconv_kernel<<<dim3(Sq / 32, HDn / 32, Bsz * KVn), dim3(32, 8), 0, stream>>>(
        C3b, Vtb);

    // --- attention: 256 uniform blocks (complementary 128-row tile pairs) ---
    fattn_kernel<<<Bsz * Hn * 8, 512, 0, stream>>>(Qb, Kb, Vtb, AOb);

    // --- output projection (fp32 out) ---
    gemm_bt_kernel<float><<<dim3(Dm / 128, M / 128), 256, 0, stream>>>(
        AOb, woT, out, M, Dm, Dm);
}

// Round 5
// 315.447 us; speedup vs baseline: 1.0668x; 1.0668x over previous
//
#include <hip/hip_runtime.h>
#include <hip/hip_bf16.h>
#include <math.h>

#define Bsz 2
#define Sq  2048
#define Dm  2048
#define Hn  16
#define KVn 4
#define HDn 128

typedef __attribute__((ext_vector_type(8))) short bf16x8;
typedef __attribute__((ext_vector_type(4))) float f32x4;

__device__ __forceinline__ short f2b(float f) {
    __hip_bfloat16 h = __float2bfloat16(f);
    return *reinterpret_cast<short*>(&h);
}
__device__ __forceinline__ float b2f(short s) {
    __hip_bfloat16 h = *reinterpret_cast<__hip_bfloat16*>(&s);
    return __bfloat162float(h);
}

// ---------------- fp32 -> bf16 elementwise (x) ----------------
__global__ __launch_bounds__(256) void f2b_kernel(
    const float* __restrict__ X, short* __restrict__ Y, int n4)
{
    int i = blockIdx.x * 256 + threadIdx.x;
    if (i >= n4) return;
    float4 v = ((const float4*)X)[i];
    short4 o;
    o.x = f2b(v.x); o.y = f2b(v.y); o.z = f2b(v.z); o.w = f2b(v.w);
    ((short4*)Y)[i] = o;
}

// ------------- ALL weights -> transposed bf16 in one launch -------------
__global__ __launch_bounds__(256) void wconv_all_kernel(
    const float* __restrict__ wq, const float* __restrict__ wk,
    const float* __restrict__ wv, const float* __restrict__ wo,
    short* __restrict__ wqkvT, short* __restrict__ woT)
{
    __shared__ float t[32][33];
    const int n0 = blockIdx.x * 32;   // global output row
    const int k0 = blockIdx.y * 32;
    const int tx = threadIdx.x, ty = threadIdx.y;

    const float* W; int Nsec, nloc; short* dst;
    if (n0 < 2048)      { W = wq; Nsec = 2048; nloc = n0;        dst = wqkvT + (size_t)n0 * Dm; }
    else if (n0 < 2560) { W = wk; Nsec = 512;  nloc = n0 - 2048; dst = wqkvT + (size_t)n0 * Dm; }
    else if (n0 < 3072) { W = wv; Nsec = 512;  nloc = n0 - 2560; dst = wqkvT + (size_t)n0 * Dm; }
    else                { W = wo; Nsec = 2048; nloc = n0 - 3072; dst = woT + (size_t)(n0 - 3072) * Dm; }

#pragma unroll
    for (int r = 0; r < 4; ++r) {
        const int row = ty + 8 * r;
        t[row][tx] = W[(size_t)(k0 + row) * Nsec + nloc + tx];
    }
    __syncthreads();
#pragma unroll
    for (int r = 0; r < 4; ++r) {
        const int row = ty + 8 * r;
        dst[(size_t)row * Dm + k0 + tx] = f2b(t[tx][row]);
    }
}

// ---------------- bf16 MFMA GEMM: C(MxN) = A(MxK) * Bt(NxK)^T ----------------
template <typename OT>
__global__ __launch_bounds__(256) void gemm_bt_kernel(
    const short* __restrict__ A, const short* __restrict__ Bt,
    OT* __restrict__ C, int M, int N, int K)
{
    __shared__ __align__(16) short As[128 * 64];
    __shared__ __align__(16) short Bs[128 * 64];

    const int tid  = threadIdx.x;
    const int w    = tid >> 6;
    const int lane = tid & 63;
    const int m16  = lane & 15;
    const int g4   = lane >> 4;
    const int wm   = w >> 1, wn = w & 1;

    const int row0 = blockIdx.y * 128;
    const int col0 = blockIdx.x * 128;

    const short* Ab = A  + (size_t)row0 * K;
    const short* Bb = Bt + (size_t)col0 * K;

    const int trow = tid >> 3;
    const int soct = (tid & 7) ^ (trow & 7);

    f32x4 acc[4][4];
#pragma unroll
    for (int i = 0; i < 4; ++i)
#pragma unroll
        for (int j = 0; j < 4; ++j) acc[i][j] = (f32x4){0.f, 0.f, 0.f, 0.f};

    for (int k0 = 0; k0 < K; k0 += 64) {
#pragma unroll
        for (int r = 0; r < 4; ++r) {
            const short* gp = Ab + (size_t)(r * 32 + trow) * K + k0 + soct * 8;
            short* lp = &As[(size_t)(r * 256 + w * 64) * 8];
            __builtin_amdgcn_global_load_lds(
                (const __attribute__((address_space(1))) void*)gp,
                (__attribute__((address_space(3))) void*)lp, 16, 0, 0);
        }
#pragma unroll
        for (int r = 0; r < 4; ++r) {
            const short* gp = Bb + (size_t)(r * 32 + trow) * K + k0 + soct * 8;
            short* lp = &Bs[(size_t)(r * 256 + w * 64) * 8];
            __builtin_amdgcn_global_load_lds(
                (const __attribute__((address_space(1))) void*)gp,
                (__attribute__((address_space(3))) void*)lp, 16, 0, 0);
        }
        __syncthreads();

#pragma unroll
        for (int kc = 0; kc < 2; ++kc) {
            bf16x8 a[4], b[4];
            const int swz = (kc * 4 + g4) ^ (m16 & 7);
#pragma unroll
            for (int s = 0; s < 4; ++s) {
                const int rowA = wm * 64 + s * 16 + m16;
                a[s] = *(const bf16x8*)&As[rowA * 64 + swz * 8];
                const int rowB = wn * 64 + s * 16 + m16;
                b[s] = *(const bf16x8*)&Bs[rowB * 64 + swz * 8];
            }
#pragma unroll
            for (int i = 0; i < 4; ++i)
#pragma unroll
                for (int j = 0; j < 4; ++j)
                    acc[i][j] = __builtin_amdgcn_mfma_f32_16x16x32_bf16(
                        a[i], b[j], acc[i][j], 0, 0, 0);
        }
        __syncthreads();
    }

#pragma unroll
    for (int i = 0; i < 4; ++i) {
        const int mbase = row0 + wm * 64 + i * 16 + g4 * 4;
#pragma unroll
        for (int j = 0; j < 4; ++j) {
            const int n = col0 + wn * 64 + j * 16 + m16;
#pragma unroll
            for (int r = 0; r < 4; ++r) {
                if constexpr (sizeof(OT) == 2)
                    C[(size_t)(mbase + r) * N + n] = f2b(acc[i][j][r]);
                else
                    C[(size_t)(mbase + r) * N + n] = acc[i][j][r];
            }
        }
    }
}

// ------------- RoPE (Q and K in one launch): one thread per (b,s,i) -------------
__global__ __launch_bounds__(256) void rope_all_kernel(
    const short* __restrict__ C3b, short* __restrict__ Qb, short* __restrict__ Kb,
    const int* __restrict__ pos_ids, float qscale, int total)
{
    int idx = blockIdx.x * blockDim.x + threadIdx.x;
    if (idx >= total) return;
    const int i = idx & 63;
    int rest = idx >> 6;
    const int s = rest % Sq;
    const int b = rest / Sq;

    const int pos = pos_ids[b * Sq + s];
    const float e   = -(float)(2 * i) * (1.0f / (float)HDn);
    const float inv = exp2f(e * 18.931568569324174f);   // log2(500000)
    const float f   = (float)pos * inv;
    float sn, c;
    sincosf(f, &sn, &c);

    const short* src = C3b + ((size_t)(b * Sq + s)) * 3072;

#pragma unroll
    for (int h = 0; h < Hn; ++h) {
        const float x1 = b2f(src[h * HDn + i]);
        const float x2 = b2f(src[h * HDn + i + 64]);
        const size_t dst = (((size_t)b * Hn + h) * Sq + s) * HDn;
        Qb[dst + i]      = f2b((x1 * c - x2 * sn) * qscale);
        Qb[dst + i + 64] = f2b((x2 * c + x1 * sn) * qscale);
    }
#pragma unroll
    for (int h = 0; h < KVn; ++h) {
        const float x1 = b2f(src[2048 + h * HDn + i]);
        const float x2 = b2f(src[2048 + h * HDn + i + 64]);
        const size_t dst = (((size_t)b * KVn + h) * Sq + s) * HDn;
        Kb[dst + i]      = f2b(x1 * c - x2 * sn);
        Kb[dst + i + 64] = f2b(x2 * c + x1 * sn);
    }
}

// ------------- V region of bf16 C3 -> transposed (B,KV,HD,S) bf16 -------------
__global__ __launch_bounds__(256) void vconv_kernel(
    const short* __restrict__ C3b, short* __restrict__ Vt)
{
    __shared__ short t[32][34];
    const int bk = blockIdx.z;
    const int b  = bk >> 2, kv = bk & 3;
    const int s0 = blockIdx.x * 32;
    const int d0 = blockIdx.y * 32;
    const int tx = threadIdx.x, ty = threadIdx.y;

#pragma unroll
    for (int r = 0; r < 4; ++r) {
        const int row = ty + 8 * r;
        t[row][tx] = C3b[((size_t)(b * Sq + s0 + row)) * 3072 + 2560 + kv * HDn + d0 + tx];
    }
    __syncthreads();
#pragma unroll
    for (int r = 0; r < 4; ++r) {
        const int row = ty + 8 * r;
        Vt[((size_t)bk * HDn + d0 + row) * Sq + s0 + tx] = t[tx][row];
    }
}

// ------------- Block-cooperative MFMA flash attention, KQ orientation -------------
// DUAL-TILE NESTED version. 512 blocks x 4 waves (2 blocks/CU -> independent
// co-resident block hides each barrier's vmcnt drain; R3 showed 1 block/CU
// costs ~20%). Block p in 0..15 owns the NESTED 64-row tile pair
// htA = 31-p, htB = p off ONE staging stream of 32-p chunks:
//   chunks 0..p      : both tiles computed, every K/V-frag LDS read shared
//                      by 2 MFMAs (2 MFMA/b128-read, vs 1 in the uniform split)
//   chunks p+1..31-p : tile A solo
// Avg staged chunks/block = 24.5 vs 33 uniform => 26% fewer LDS reads +
// staging events. Balanced mapping pairs complementary p on co-resident
// blocks: per-CU busy work uniform at 49 chunk-units.
__global__ __launch_bounds__(256, 2) void fattn_kernel(
    const short* __restrict__ Qb, const short* __restrict__ Kb,
    const short* __restrict__ Vtb, short* __restrict__ AOb)
{
    __shared__ __align__(16) short Ks[2][64 * 128];   // [buf][perm key][dim], oct-swizzled
    __shared__ __align__(16) short Vs[2][128 * 64];   // [buf][dim][key], oct-swizzled

    const int tid  = threadIdx.x;
    const int w    = tid >> 6;
    const int lane = tid & 63;
    const int m16  = lane & 15;
    const int g4   = lane >> 4;

    // balanced mapping: blocks i and i+256 get complementary p
    const int i    = blockIdx.x;
    const int half = i >> 8;
    const int k4   = i & 15;
    const int p    = half ? k4 : 15 - k4;
    const int h    = (i >> 4) & 15;
    const int b    = i >> 8;
    const int kv   = h >> 2;

    const int htA = 31 - p, htB = p;    // nested 64-row tiles
    const int nch = htA + 1;            // staged/computed chunks: 32-p
    const int qA  = htA * 64 + w * 16;  // this wave's q-row base, tile A
    const int qB  = htB * 64 + w * 16;

    // Q fragments for both tiles
    bf16x8 qfA[4], qfB[4];
    {
        const short* qpA = Qb + (((size_t)b * Hn + h) * Sq + qA + m16) * HDn + g4 * 8;
        const short* qpB = Qb + (((size_t)b * Hn + h) * Sq + qB + m16) * HDn + g4 * 8;
#pragma unroll
        for (int c = 0; c < 4; ++c) {
            qfA[c] = *(const bf16x8*)(qpA + c * 32);
            qfB[c] = *(const bf16x8*)(qpB + c * 32);
        }
    }

    const short* kbase = Kb  + ((size_t)b * KVn + kv) * Sq * HDn;
    const short* vbase = Vtb + ((size_t)b * KVn + kv) * (size_t)HDn * Sq;

    // staging source pointers (loop-invariant part); 256 threads x r=0..3 x 16B
    const short* gpK[4];
    const short* gpV[4];
#pragma unroll
    for (int r = 0; r < 4; ++r) {
        const int ci = r * 256 + tid;
        const int R  = ci >> 4, o = ci & 15;          // LDS K row, oct
        const int hf = (R >> 5) & 1, Rl = R & 31;
        const int phys = hf * 32 + ((Rl >> 2) & 3) * 8 + ((Rl >> 4) & 1) * 4 + (Rl & 3);
        gpK[r] = kbase + (size_t)phys * HDn + (o ^ (R & 7)) * 8;
        const int d = ci >> 3, ov = ci & 7;           // V dim row, oct
        gpV[r] = vbase + (size_t)d * Sq + (ov ^ (d & 7)) * 8;
    }

    auto stage = [&](int ktE, int buf) {
#pragma unroll
        for (int r = 0; r < 4; ++r) {
            const short* gp = gpK[r] + (size_t)ktE * HDn;
            short* lp = &Ks[buf][(size_t)(r * 256 + w * 64) * 8];
            __builtin_amdgcn_global_load_lds(
                (const __attribute__((address_space(1))) void*)gp,
                (__attribute__((address_space(3))) void*)lp, 16, 0, 0);
        }
#pragma unroll
        for (int r = 0; r < 4; ++r) {
            const short* gp = gpV[r] + ktE;
            short* lp = &Vs[buf][(size_t)(r * 256 + w * 64) * 8];
            __builtin_amdgcn_global_load_lds(
                (const __attribute__((address_space(1))) void*)gp,
                (__attribute__((address_space(3))) void*)lp, 16, 0, 0);
        }
    };

    f32x4 OtA[8], OtB[8];
#pragma unroll
    for (int t = 0; t < 8; ++t) {
        OtA[t] = (f32x4){0.f, 0.f, 0.f, 0.f};
        OtB[t] = (f32x4){0.f, 0.f, 0.f, 0.f};
    }
    float mA = -1e30f, lA = 0.f, mB = -1e30f, lB = 0.f;

    stage(0, 0);
    int gpar = 0;

    // ================= dual phase: chunks 0..p (tile B ends at p) =========
    for (int ch = 0; ch <= p; ++ch) {
        const int cur = gpar & 1; gpar ^= 1;
        const int kt  = ch << 6;

        __syncthreads();                     // buf[cur] staged; prior readers of buf[cur^1] done
        stage((ch + 1) << 6, cur ^ 1);       // ch+1 <= p+1 <= 31-p always valid

        const bool dgB = (ch == p);          // tile B diagonal chunk
        const short* KsC = Ks[cur];
        const short* VsC = Vs[cur];

        // ---- scores, K-frag read shared by both tiles ----
        f32x4 sc0[4], sc1[4];
        __builtin_amdgcn_s_setprio(1);
#pragma unroll
        for (int f = 0; f < 4; ++f) {
            f32x4 a0 = (f32x4){0.f, 0.f, 0.f, 0.f};
            f32x4 a1 = (f32x4){0.f, 0.f, 0.f, 0.f};
            const int krow = f * 16 + m16;
#pragma unroll
            for (int c = 0; c < 4; ++c) {
                bf16x8 kf = *(const bf16x8*)&KsC[krow * 128 + (((c * 4 + g4) ^ (m16 & 7)) * 8)];
                a0 = __builtin_amdgcn_mfma_f32_16x16x32_bf16(kf, qfA[c], a0, 0, 0, 0);
                a1 = __builtin_amdgcn_mfma_f32_16x16x32_bf16(kf, qfB[c], a1, 0, 0, 0);
            }
            sc0[f] = a0; sc1[f] = a1;
        }
        __builtin_amdgcn_s_setprio(0);

        // tile A never hits its diagonal during the dual phase (htA >= 16 > p)
        if (dgB) {
            const int qg = qB + m16;
#pragma unroll
            for (int f = 0; f < 4; ++f)
#pragma unroll
                for (int ii = 0; ii < 4; ++ii) {
                    const int kg = kt + (f >> 1) * 32 + g4 * 8 + (f & 1) * 4 + ii;
                    if (kg > qg) sc1[f][ii] = -1e30f;
                }
        }

        // ---- online softmax, tile A ----
        bf16x8 pf0[2], pf1[2];
        {
            float mx = sc0[0][0];
#pragma unroll
            for (int f = 0; f < 4; ++f)
#pragma unroll
                for (int ii = 0; ii < 4; ++ii) mx = fmaxf(mx, sc0[f][ii]);
            mx = fmaxf(mx, __shfl_xor(mx, 16));
            mx = fmaxf(mx, __shfl_xor(mx, 32));
            if (!__all(mx <= mA + 8.0f)) {
                const float nm = fmaxf(mA, mx);
                const float alpha = exp2f(mA - nm);
                mA = nm; lA *= alpha;
#pragma unroll
                for (int t = 0; t < 8; ++t)
#pragma unroll
                    for (int ii = 0; ii < 4; ++ii) OtA[t][ii] *= alpha;
            }
            float ps = 0.f;
#pragma unroll
            for (int f = 0; f < 4; ++f)
#pragma unroll
                for (int ii = 0; ii < 4; ++ii) {
                    sc0[f][ii] = exp2f(sc0[f][ii] - mA);
                    ps += sc0[f][ii];
                }
            ps += __shfl_xor(ps, 16);
            ps += __shfl_xor(ps, 32);
            lA += ps;
#pragma unroll
            for (int hf = 0; hf < 2; ++hf) {
                bf16x8 pk;
#pragma unroll
                for (int j8 = 0; j8 < 8; ++j8)
                    pk[j8] = f2b(j8 < 4 ? sc0[hf * 2][j8] : sc0[hf * 2 + 1][j8 - 4]);
                pf0[hf] = pk;
            }
        }
        // ---- online softmax, tile B ----
        {
            float mx = sc1[0][0];
#pragma unroll
            for (int f = 0; f < 4; ++f)
#pragma unroll
                for (int ii = 0; ii < 4; ++ii) mx = fmaxf(mx, sc1[f][ii]);
            mx = fmaxf(mx, __shfl_xor(mx, 16));
            mx = fmaxf(mx, __shfl_xor(mx, 32));
            if (!__all(mx <= mB + 8.0f)) {
                const float nm = fmaxf(mB, mx);
                const float alpha = exp2f(mB - nm);
                mB = nm; lB *= alpha;
#pragma unroll
                for (int t = 0; t < 8; ++t)
#pragma unroll
                    for (int ii = 0; ii < 4; ++ii) OtB[t][ii] *= alpha;
            }
            float ps = 0.f;
#pragma unroll
            for (int f = 0; f < 4; ++f)
#pragma unroll
                for (int ii = 0; ii < 4; ++ii) {
                    sc1[f][ii] = exp2f(sc1[f][ii] - mB);
                    ps += sc1[f][ii];
                }
            ps += __shfl_xor(ps, 16);
            ps += __shfl_xor(ps, 32);
            lB += ps;
#pragma unroll
            for (int hf = 0; hf < 2; ++hf) {
                bf16x8 pk;
#pragma unroll
                for (int j8 = 0; j8 < 8; ++j8)
                    pk[j8] = f2b(j8 < 4 ? sc1[hf * 2][j8] : sc1[hf * 2 + 1][j8 - 4]);
                pf1[hf] = pk;
            }
        }

        // ---- PV: V-frag read shared by both tiles ----
        __builtin_amdgcn_s_setprio(1);
#pragma unroll
        for (int t = 0; t < 8; ++t) {
            const int d = t * 16 + m16;
            bf16x8 vfa = *(const bf16x8*)&VsC[d * 64 + ((g4 ^ (d & 7)) * 8)];
            bf16x8 vfb = *(const bf16x8*)&VsC[d * 64 + (((4 + g4) ^ (d & 7)) * 8)];
            OtA[t] = __builtin_amdgcn_mfma_f32_16x16x32_bf16(vfa, pf0[0], OtA[t], 0, 0, 0);
            OtA[t] = __builtin_amdgcn_mfma_f32_16x16x32_bf16(vfb, pf0[1], OtA[t], 0, 0, 0);
            OtB[t] = __builtin_amdgcn_mfma_f32_16x16x32_bf16(vfa, pf1[0], OtB[t], 0, 0, 0);
            OtB[t] = __builtin_amdgcn_mfma_f32_16x16x32_bf16(vfb, pf1[1], OtB[t], 0, 0, 0);
        }
        __builtin_amdgcn_s_setprio(0);
    }

    // tile B complete -> write its output now
    {
        const float inv = 1.0f / lB;
        short* op = AOb + ((size_t)(b * Sq + qB + m16)) * (Hn * HDn) + h * HDn + g4 * 4;
#pragma unroll
        for (int t = 0; t < 8; ++t) {
            short4 o;
            o.x = f2b(OtB[t][0] * inv);
            o.y = f2b(OtB[t][1] * inv);
            o.z = f2b(OtB[t][2] * inv);
            o.w = f2b(OtB[t][3] * inv);
            *(short4*)(op + t * 16) = o;
        }
    }

    // ================= solo phase: chunks p+1..31-p (tile A only) =========
    for (int ch = p + 1; ch < nch; ++ch) {
        const int cur = gpar & 1; gpar ^= 1;
        const int kt  = ch << 6;

        __syncthreads();
        if (ch + 1 < nch) stage((ch + 1) << 6, cur ^ 1);

        const bool dgA = (ch == nch - 1);
        const short* KsC = Ks[cur];
        const short* VsC = Vs[cur];

        f32x4 sc[4];
        __builtin_amdgcn_s_setprio(1);
#pragma unroll
        for (int f = 0; f < 4; ++f) {
            f32x4 a = (f32x4){0.f, 0.f, 0.f, 0.f};
            const int krow = f * 16 + m16;
#pragma unroll
            for (int c = 0; c < 4; ++c) {
                bf16x8 kf = *(const bf16x8*)&KsC[krow * 128 + (((c * 4 + g4) ^ (m16 & 7)) * 8)];
                a = __builtin_amdgcn_mfma_f32_16x16x32_bf16(kf, qfA[c], a, 0, 0, 0);
            }
            sc[f] = a;
        }
        __builtin_amdgcn_s_setprio(0);

        if (dgA) {
            const int qg = qA + m16;
#pragma unroll
            for (int f = 0; f < 4; ++f)
#pragma unroll
                for (int ii = 0; ii < 4; ++ii) {
                    const int kg = kt + (f >> 1) * 32 + g4 * 8 + (f & 1) * 4 + ii;
                    if (kg > qg) sc[f][ii] = -1e30f;
                }
        }

        float mx = sc[0][0];
#pragma unroll
        for (int f = 0; f < 4; ++f)
#pragma unroll
            for (int ii = 0; ii < 4; ++ii) mx = fmaxf(mx, sc[f][ii]);
        mx = fmaxf(mx, __shfl_xor(mx, 16));
        mx = fmaxf(mx, __shfl_xor(mx, 32));
        if (!__all(mx <= mA + 8.0f)) {
            const float nm = fmaxf(mA, mx);
            const float alpha = exp2f(mA - nm);
            mA = nm; lA *= alpha;
#pragma unroll
            for (int t = 0; t < 8; ++t)
#pragma unroll
                for (int ii = 0; ii < 4; ++ii) OtA[t][ii] *= alpha;
        }
        float ps = 0.f;
#pragma unroll
        for (int f = 0; f < 4; ++f)
#pragma unroll
            for (int ii = 0; ii < 4; ++ii) {
                sc[f][ii] = exp2f(sc[f][ii] - mA);
                ps += sc[f][ii];
            }
        ps += __shfl_xor(ps, 16);
        ps += __shfl_xor(ps, 32);
        lA += ps;

        bf16x8 pf[2];
#pragma unroll
        for (int hf = 0; hf < 2; ++hf) {
            bf16x8 pk;
#pragma unroll
            for (int j8 = 0; j8 < 8; ++j8)
                pk[j8] = f2b(j8 < 4 ? sc[hf * 2][j8] : sc[hf * 2 + 1][j8 - 4]);
            pf[hf] = pk;
        }

        __builtin_amdgcn_s_setprio(1);
#pragma unroll
        for (int t = 0; t < 8; ++t) {
            const int d = t * 16 + m16;
            bf16x8 vfa = *(const bf16x8*)&VsC[d * 64 + ((g4 ^ (d & 7)) * 8)];
            bf16x8 vfb = *(const bf16x8*)&VsC[d * 64 + (((4 + g4) ^ (d & 7)) * 8)];
            OtA[t] = __builtin_amdgcn_mfma_f32_16x16x32_bf16(vfa, pf[0], OtA[t], 0, 0, 0);
            OtA[t] = __builtin_amdgcn_mfma_f32_16x16x32_bf16(vfb, pf[1], OtA[t], 0, 0, 0);
        }
        __builtin_amdgcn_s_setprio(0);
    }

    // tile A epilogue
    {
        const float inv = 1.0f / lA;
        short* op = AOb + ((size_t)(b * Sq + qA + m16)) * (Hn * HDn) + h * HDn + g4 * 4;
#pragma unroll
        for (int t = 0; t < 8; ++t) {
            short4 o;
            o.x = f2b(OtA[t][0] * inv);
            o.y = f2b(OtA[t][1] * inv);
            o.z = f2b(OtA[t][2] * inv);
            o.w = f2b(OtA[t][3] * inv);
            *(short4*)(op + t * 16) = o;
        }
    }
}

extern "C" void kernel_launch(void* const* d_in, const int* in_sizes, int n_in,
                              void* d_out, int out_size, void* d_ws, size_t ws_size,
                              hipStream_t stream)
{
    const float* x   = (const float*)d_in[0];
    const float* wq  = (const float*)d_in[1];
    const float* wk  = (const float*)d_in[2];
    const float* wv  = (const float*)d_in[3];
    const float* wo  = (const float*)d_in[4];
    const int* pos   = (const int*)d_in[6];
    float* out = (float*)d_out;

    const int M = Bsz * Sq;            // 4096
    const size_t nX  = (size_t)M * Dm; // 8388608

    short* xb    = (short*)d_ws;
    short* wqkvT = xb + nX;                       // 3072 x 2048
    short* woT   = wqkvT + (size_t)3072 * Dm;     // 2048 x 2048
    short* C3b   = woT + (size_t)Dm * Dm;         // 4096 x 3072 bf16
    short* Qb    = C3b + (size_t)M * 3072;
    short* Kb    = Qb + nX;
    short* Vtb   = Kb + (size_t)Bsz * KVn * Sq * HDn;
    short* AOb   = Vtb + (size_t)Bsz * KVn * Sq * HDn;

    // --- conversions (2 launches) ---
    f2b_kernel<<<(nX / 4 + 255) / 256, 256, 0, stream>>>(x, xb, nX / 4);
    wconv_all_kernel<<<dim3(5120 / 32, Dm / 32), dim3(32, 8), 0, stream>>>(
        wq, wk, wv, wo, wqkvT, woT);

    // --- fused QKV projection -> bf16 C3 ---
    gemm_bt_kernel<short><<<dim3(3072 / 128, M / 128), 256, 0, stream>>>(
        xb, wqkvT, C3b, M, 3072, Dm);

    // --- RoPE (Q+K) in one launch ---
    {
        const float qscale = 0.08838834764831845f * 1.4426950408889634f;
        int tot = Bsz * Sq * 64;
        rope_all_kernel<<<(tot + 255) / 256, 256, 0, stream>>>(
            C3b, Qb, Kb, pos, qscale, tot);
    }
    vconv_kernel<<<dim3(Sq / 32, HDn / 32, Bsz * KVn), dim3(32, 8), 0, stream>>>(
        C3b, Vtb);

    // --- attention: 512 blocks, nested dual-tile, shared-read staging ---
    fattn_kernel<<<Bsz * Hn * 16, 256, 0, stream>>>(Qb, Kb, Vtb, AOb);

    // --- output projection (fp32 out) ---
    gemm_bt_kernel<float><<<dim3(Dm / 128, M / 128), 256, 0, stream>>>(
        AOb, woT, out, M, Dm, Dm);
}